// Round 5
// baseline (196.472 us; speedup 1.0000x reference)
//
#include <hip/hip_runtime.h>
#include <math.h>

#define EPS 1e-8f

// ---- ws layout (float offsets): weights transposed to [k][j] + basis ----
#define OFF_CW1T 0        // [128][128]
#define OFF_CW2T 16384    // [128][256]
#define OFF_CW3T 49152    // [256][20]
#define OFF_WW1T 54272    // [128][64]
#define OFF_WW2T 62464    // [64][128]
#define OFF_WW3T 70656    // [128][10]
#define OFF_BASIS 71936   // [1024][10]

// ---------------------------------------------------------------------------
__global__ __launch_bounds__(256) void prep_kernel(
    const float* __restrict__ cw1, const float* __restrict__ cw2, const float* __restrict__ cw3,
    const float* __restrict__ ww1, const float* __restrict__ ww2, const float* __restrict__ ww3,
    float* __restrict__ ws)
{
  int id = blockIdx.x * 256 + threadIdx.x;
  if (id < 16384) { int k = id >> 7, j = id & 127; ws[OFF_CW1T + id] = cw1[j*128 + k]; return; }
  id -= 16384;
  if (id < 32768) { int k = id >> 8, j = id & 255; ws[OFF_CW2T + (k*256 + j)] = cw2[j*128 + k]; return; }
  id -= 32768;
  if (id < 5120)  { int k = id / 20, j = id % 20;  ws[OFF_CW3T + id] = cw3[j*256 + k]; return; }
  id -= 5120;
  if (id < 8192)  { int k = id >> 6, j = id & 63;  ws[OFF_WW1T + id] = ww1[j*128 + k]; return; }
  id -= 8192;
  if (id < 8192)  { int k = id >> 7, j = id & 127; ws[OFF_WW2T + id] = ww2[j*64  + k]; return; }
  id -= 8192;
  if (id < 1280)  { int k = id / 10, j = id % 10;  ws[OFF_WW3T + id] = ww3[j*128 + k]; return; }
  id -= 1280;
  if (id < 1024) {
    int f = id;
    float t = (float)f * (1.0f / 1023.0f);
    float v[10]; float s = 0.f;
    #pragma unroll
    for (int p = 0; p < 10; ++p) {
      float d = t - (float)p * (1.0f / 9.0f);
      float e = expf(-d * d * 50.0f);
      v[p] = e; s += e;
    }
    float inv = 1.0f / (s + EPS);
    #pragma unroll
    for (int p = 0; p < 10; ++p) ws[OFF_BASIS + f*10 + p] = v[p] * inv;
  }
}

// ---------------------------------------------------------------------------
// Fully fused, 32 rows/block, 512 threads (8 waves), grid 512 (2 blocks/CU).
// lane l -> row r=l>>1, side sd=l&1; (wave, side) = 16 column slices.
// Weight loads are per-lane VMEM (coalesced to one 64B line per wave) ->
// deeply pipelined vmcnt, no SMEM/lgkm serialization.
// LDS rows rotate-swizzled by +r: bank = (k+r)&31, conflict-free.
// ---------------------------------------------------------------------------
__global__ __launch_bounds__(512, 4) void fused_kernel(
    const float* __restrict__ x,
    const float* __restrict__ cb1, const float* __restrict__ cb2, const float* __restrict__ cb3,
    const float* __restrict__ wb1, const float* __restrict__ wb2, const float* __restrict__ wb3,
    const float* __restrict__ ws, float* __restrict__ out)
{
  __shared__ float xs[4096];     // x   [32][128] rotate(+r)
  __shared__ float hb[4096];     // h1  [32][128] rotate(+r)
  __shared__ float hv[2048];     // hv1 [32][64]  rotate(+r)
  __shared__ float vbuf[320];    // logit partials -> softmax w [32][10]
  __shared__ float cpbuf[640];   // cp partials -> wm [32][20]

  const int tid = threadIdx.x;
  const int l   = tid & 63;
  const int w   = tid >> 6;      // 0..7
  const int r   = l >> 1;        // row 0..31
  const int sd  = l & 1;         // side 0/1
  const int b0  = blockIdx.x * 32;

  const float* CW1T = ws + OFF_CW1T;
  const float* CW2T = ws + OFF_CW2T;
  const float* CW3T = ws + OFF_CW3T;
  const float* WW1T = ws + OFF_WW1T;
  const float* WW2T = ws + OFF_WW2T;
  const float* WW3T = ws + OFF_WW3T;

  // ---- P0: stage x [32][128] -> xs (rotate +row), zero reduce buffers
  {
    const float4* xg = (const float4*)(x + (size_t)b0 * 128);
    #pragma unroll
    for (int i = tid; i < 1024; i += 512) {
      float4 v = xg[i];
      int rr = i >> 5, kk = (i & 31) << 2;
      float* row = xs + rr * 128;
      row[(kk + 0 + rr) & 127] = v.x;
      row[(kk + 1 + rr) & 127] = v.y;
      row[(kk + 2 + rr) & 127] = v.z;
      row[(kk + 3 + rr) & 127] = v.w;
    }
    if (tid < 320) vbuf[tid] = 0.f;
    cpbuf[tid] = 0.f;
    if (tid < 128) cpbuf[512 + tid] = 0.f;
  }
  __syncthreads();   // B1

  // ---- P1: L1 (cp, 8 cols @ cb) + V1 (w, 4 cols @ vb), K=128, fused
  {
    const int cb = 16 * w + 8 * sd;   // L1 col base (N=128)
    const int vb = 8 * w + 4 * sd;    // V1 col base (N=64)
    float accL[8], accV[4];
    #pragma unroll
    for (int j = 0; j < 8; ++j) accL[j] = cb1[cb + j];
    #pragma unroll
    for (int j = 0; j < 4; ++j) accV[j] = wb1[vb + j];
    const float* w1 = CW1T + cb;
    const float* v1 = WW1T + vb;
    const float* xrow = xs + r * 128;
    #pragma unroll 4
    for (int k = 0; k < 128; ++k) {
      float xv = xrow[(k + r) & 127];
      float4 a = *(const float4*)(w1 + (k << 7));
      float4 b = *(const float4*)(w1 + (k << 7) + 4);
      float4 c = *(const float4*)(v1 + (k << 6));
      accL[0] = fmaf(xv, a.x, accL[0]);
      accL[1] = fmaf(xv, a.y, accL[1]);
      accL[2] = fmaf(xv, a.z, accL[2]);
      accL[3] = fmaf(xv, a.w, accL[3]);
      accL[4] = fmaf(xv, b.x, accL[4]);
      accL[5] = fmaf(xv, b.y, accL[5]);
      accL[6] = fmaf(xv, b.z, accL[6]);
      accL[7] = fmaf(xv, b.w, accL[7]);
      accV[0] = fmaf(xv, c.x, accV[0]);
      accV[1] = fmaf(xv, c.y, accV[1]);
      accV[2] = fmaf(xv, c.z, accV[2]);
      accV[3] = fmaf(xv, c.w, accV[3]);
    }
    float* hrow = hb + r * 128;
    #pragma unroll
    for (int j = 0; j < 8; ++j) hrow[(cb + j + r) & 127] = fmaxf(accL[j], 0.f);
    float* hvrow = hv + r * 64;
    #pragma unroll
    for (int j = 0; j < 4; ++j) hvrow[(vb + j + r) & 63] = fmaxf(accV[j], 0.f);
  }
  __syncthreads();   // B2

  // ---- P2: V2 (8 cols, K=64) + fused V3 -> logit partials -> vbuf
  {
    const int cb = 16 * w + 8 * sd;   // V2 col base (N=128)
    float a2[8];
    #pragma unroll
    for (int j = 0; j < 8; ++j) a2[j] = wb2[cb + j];
    const float* v2 = WW2T + cb;
    const float* hvrow = hv + r * 64;
    #pragma unroll 4
    for (int k = 0; k < 64; ++k) {
      float hvv = hvrow[(k + r) & 63];
      float4 a = *(const float4*)(v2 + (k << 7));
      float4 b = *(const float4*)(v2 + (k << 7) + 4);
      a2[0] = fmaf(hvv, a.x, a2[0]);
      a2[1] = fmaf(hvv, a.y, a2[1]);
      a2[2] = fmaf(hvv, a.z, a2[2]);
      a2[3] = fmaf(hvv, a.w, a2[3]);
      a2[4] = fmaf(hvv, b.x, a2[4]);
      a2[5] = fmaf(hvv, b.y, a2[5]);
      a2[6] = fmaf(hvv, b.z, a2[6]);
      a2[7] = fmaf(hvv, b.w, a2[7]);
    }
    float vp[10];
    #pragma unroll
    for (int j = 0; j < 10; ++j) vp[j] = 0.f;
    #pragma unroll
    for (int c = 0; c < 8; ++c) {
      float h = fmaxf(a2[c], 0.f);
      const float* t = WW3T + (cb + c) * 10;
      #pragma unroll
      for (int j = 0; j < 10; j += 2) {
        float2 tv = *(const float2*)(t + j);
        vp[j]   = fmaf(h, tv.x, vp[j]);
        vp[j+1] = fmaf(h, tv.y, vp[j+1]);
      }
    }
    #pragma unroll
    for (int j = 0; j < 10; ++j) atomicAdd(vbuf + r * 10 + j, vp[j]);
  }
  __syncthreads();   // B3

  // ---- P3: softmax (threads 0..31, one row each; in-place in vbuf)
  if (tid < 32) {
    float lg[10]; float m = -1e30f;
    #pragma unroll
    for (int j = 0; j < 10; ++j) { lg[j] = vbuf[tid*10 + j] + wb3[j]; m = fmaxf(m, lg[j]); }
    float sum = 0.f;
    #pragma unroll
    for (int j = 0; j < 10; ++j) { float e = expf(lg[j] - m); lg[j] = e; sum += e; }
    float inv = __builtin_amdgcn_rcpf(sum);
    #pragma unroll
    for (int j = 0; j < 10; ++j) vbuf[tid*10 + j] = lg[j] * inv;
  }

  // ---- P4: L2 (16 cols, K=128) + fused L3 -> cp partials -> cpbuf
  {
    const int cb = 32 * w + 16 * sd;  // L2 col base (N=256)
    float a3[16];
    #pragma unroll
    for (int j = 0; j < 16; ++j) a3[j] = cb2[cb + j];
    const float* w2 = CW2T + cb;
    const float* hrow = hb + r * 128;
    #pragma unroll 2
    for (int k = 0; k < 128; ++k) {
      float hh = hrow[(k + r) & 127];
      float4 a = *(const float4*)(w2 + (k << 8));
      float4 b = *(const float4*)(w2 + (k << 8) + 4);
      float4 c = *(const float4*)(w2 + (k << 8) + 8);
      float4 d = *(const float4*)(w2 + (k << 8) + 12);
      a3[0]  = fmaf(hh, a.x, a3[0]);
      a3[1]  = fmaf(hh, a.y, a3[1]);
      a3[2]  = fmaf(hh, a.z, a3[2]);
      a3[3]  = fmaf(hh, a.w, a3[3]);
      a3[4]  = fmaf(hh, b.x, a3[4]);
      a3[5]  = fmaf(hh, b.y, a3[5]);
      a3[6]  = fmaf(hh, b.z, a3[6]);
      a3[7]  = fmaf(hh, b.w, a3[7]);
      a3[8]  = fmaf(hh, c.x, a3[8]);
      a3[9]  = fmaf(hh, c.y, a3[9]);
      a3[10] = fmaf(hh, c.z, a3[10]);
      a3[11] = fmaf(hh, c.w, a3[11]);
      a3[12] = fmaf(hh, d.x, a3[12]);
      a3[13] = fmaf(hh, d.y, a3[13]);
      a3[14] = fmaf(hh, d.z, a3[14]);
      a3[15] = fmaf(hh, d.w, a3[15]);
    }
    float cp[20];
    #pragma unroll
    for (int j = 0; j < 20; ++j) cp[j] = 0.f;
    #pragma unroll
    for (int c = 0; c < 16; ++c) {
      float h = fmaxf(a3[c], 0.f);
      const float* t = CW3T + (cb + c) * 20;
      #pragma unroll
      for (int j = 0; j < 20; j += 4) {
        float4 tv = *(const float4*)(t + j);
        cp[j]   = fmaf(h, tv.x, cp[j]);
        cp[j+1] = fmaf(h, tv.y, cp[j+1]);
        cp[j+2] = fmaf(h, tv.z, cp[j+2]);
        cp[j+3] = fmaf(h, tv.w, cp[j+3]);
      }
    }
    #pragma unroll
    for (int j = 0; j < 20; ++j) atomicAdd(cpbuf + r * 20 + j, cp[j]);
  }
  __syncthreads();   // B4

  // ---- P5: wm = w * cp_mean (threads 0..31; wm into cpbuf[r][0..10))
  if (tid < 32) {
    #pragma unroll
    for (int p = 0; p < 10; ++p) {
      float s0 = cpbuf[tid*20 + 2*p]     + cb3[2*p];
      float s1 = cpbuf[tid*20 + 2*p + 1] + cb3[2*p + 1];
      float cm = 0.5f * (tanhf(s0) + tanhf(s1));
      cpbuf[tid*20 + p] = vbuf[tid*10 + p] * cm;
    }
  }
  __syncthreads();   // B5

  // ---- P6: combine + output. thread = 2 consecutive f-cols x 32 rows.
  {
    const float* BAS = ws + OFF_BASIS;
    const int f0 = tid * 2;
    float bas[20];
    {
      const float4* bp = (const float4*)(BAS + f0 * 10);
      #pragma unroll
      for (int i = 0; i < 5; ++i) {
        float4 v = bp[i];
        bas[4*i+0] = v.x; bas[4*i+1] = v.y; bas[4*i+2] = v.z; bas[4*i+3] = v.w;
      }
    }
    for (int rr = 0; rr < 32; ++rr) {
      float wv[10], wm[10];
      #pragma unroll
      for (int p = 0; p < 10; p += 2) {
        float2 a = *(const float2*)(vbuf + rr*10 + p);
        wv[p] = a.x; wv[p+1] = a.y;
        float2 b = *(const float2*)(cpbuf + rr*20 + p);
        wm[p] = b.x; wm[p+1] = b.y;
      }
      float n0 = 0.f, d0 = EPS, n1 = 0.f, d1 = EPS;
      #pragma unroll
      for (int p = 0; p < 10; ++p) {
        n0 = fmaf(bas[p],      wm[p], n0);
        d0 = fmaf(bas[p],      wv[p], d0);
        n1 = fmaf(bas[10 + p], wm[p], n1);
        d1 = fmaf(bas[10 + p], wv[p], d1);
      }
      float2 o;
      o.x = n0 * __builtin_amdgcn_rcpf(d0);
      o.y = n1 * __builtin_amdgcn_rcpf(d1);
      *(float2*)(out + (size_t)(b0 + rr) * 1024 + f0) = o;
    }
  }
}

// ---------------------------------------------------------------------------
extern "C" void kernel_launch(void* const* d_in, const int* in_sizes, int n_in,
                              void* d_out, int out_size, void* d_ws, size_t ws_size,
                              hipStream_t stream)
{
  const float* x   = (const float*)d_in[0];
  const float* cw1 = (const float*)d_in[1];
  const float* cb1 = (const float*)d_in[2];
  const float* cw2 = (const float*)d_in[3];
  const float* cb2 = (const float*)d_in[4];
  const float* cw3 = (const float*)d_in[5];
  const float* cb3 = (const float*)d_in[6];
  const float* ww1 = (const float*)d_in[7];
  const float* wb1 = (const float*)d_in[8];
  const float* ww2 = (const float*)d_in[9];
  const float* wb2 = (const float*)d_in[10];
  const float* ww3 = (const float*)d_in[11];
  const float* wb3 = (const float*)d_in[12];
  float* ws  = (float*)d_ws;
  float* out = (float*)d_out;

  prep_kernel<<<285, 256, 0, stream>>>(cw1, cw2, cw3, ww1, ww2, ww3, ws);
  fused_kernel<<<512, 512, 0, stream>>>(x, cb1, cb2, cb3, wb1, wb2, wb3, ws, out);
}

// Round 6
// 129.384 us; speedup vs baseline: 1.5185x; 1.5185x over previous
//
#include <hip/hip_runtime.h>
#include <math.h>

#define EPS 1e-8f

// ---- ws layout (float offsets): weights transposed to [k][j] + basis ----
#define OFF_CW1T 0        // [128][128]
#define OFF_CW2T 16384    // [128][256]
#define OFF_CW3T 49152    // [256][20]
#define OFF_WW1T 54272    // [128][64]
#define OFF_WW2T 62464    // [64][128]
#define OFF_WW3T 70656    // [128][10]
#define OFF_BASIS 71936   // [1024][10]

// ---------------------------------------------------------------------------
__global__ __launch_bounds__(256) void prep_kernel(
    const float* __restrict__ cw1, const float* __restrict__ cw2, const float* __restrict__ cw3,
    const float* __restrict__ ww1, const float* __restrict__ ww2, const float* __restrict__ ww3,
    float* __restrict__ ws)
{
  int id = blockIdx.x * 256 + threadIdx.x;
  if (id < 16384) { int k = id >> 7, j = id & 127; ws[OFF_CW1T + id] = cw1[j*128 + k]; return; }
  id -= 16384;
  if (id < 32768) { int k = id >> 8, j = id & 255; ws[OFF_CW2T + (k*256 + j)] = cw2[j*128 + k]; return; }
  id -= 32768;
  if (id < 5120)  { int k = id / 20, j = id % 20;  ws[OFF_CW3T + id] = cw3[j*256 + k]; return; }
  id -= 5120;
  if (id < 8192)  { int k = id >> 6, j = id & 63;  ws[OFF_WW1T + id] = ww1[j*128 + k]; return; }
  id -= 8192;
  if (id < 8192)  { int k = id >> 7, j = id & 127; ws[OFF_WW2T + id] = ww2[j*64  + k]; return; }
  id -= 8192;
  if (id < 1280)  { int k = id / 10, j = id % 10;  ws[OFF_WW3T + id] = ww3[j*128 + k]; return; }
  id -= 1280;
  if (id < 1024) {
    int f = id;
    float t = (float)f * (1.0f / 1023.0f);
    float v[10]; float s = 0.f;
    #pragma unroll
    for (int p = 0; p < 10; ++p) {
      float d = t - (float)p * (1.0f / 9.0f);
      float e = expf(-d * d * 50.0f);
      v[p] = e; s += e;
    }
    float inv = 1.0f / (s + EPS);
    #pragma unroll
    for (int p = 0; p < 10; ++p) ws[OFF_BASIS + f*10 + p] = v[p] * inv;
  }
}

// ---------------------------------------------------------------------------
// helpers: register fills from transposed LDS [k][row] (stride 65), and pure
// s_load + v_fma quarter loops (activations in regs, static indices).
// ---------------------------------------------------------------------------
__device__ __forceinline__ void fill32(float (&xr)[32], const float* __restrict__ lds,
                                       int koff, int l)
{
  const float* base = lds + koff * 65 + l;
  #pragma unroll
  for (int k = 0; k < 32; ++k) xr[k] = base[k * 65];
}

// L1+V1 quarter: 8 cp cols + 4 w cols (wave-uniform), 12 FMA per k
__device__ __forceinline__ void q_l1v1(const float (&xr)[32], int koff,
                                       const float* __restrict__ w1,
                                       const float* __restrict__ v1,
                                       float (&accL)[8], float (&accV)[4])
{
  #pragma unroll
  for (int k = 0; k < 32; ++k) {
    const int kk = koff + k;
    float xv = xr[k];
    float4 a = *(const float4*)(w1 + kk*128);
    float4 b = *(const float4*)(w1 + kk*128 + 4);
    float4 c = *(const float4*)(v1 + kk*64);
    accL[0] = fmaf(xv, a.x, accL[0]);
    accL[1] = fmaf(xv, a.y, accL[1]);
    accL[2] = fmaf(xv, a.z, accL[2]);
    accL[3] = fmaf(xv, a.w, accL[3]);
    accL[4] = fmaf(xv, b.x, accL[4]);
    accL[5] = fmaf(xv, b.y, accL[5]);
    accL[6] = fmaf(xv, b.z, accL[6]);
    accL[7] = fmaf(xv, b.w, accL[7]);
    accV[0] = fmaf(xv, c.x, accV[0]);
    accV[1] = fmaf(xv, c.y, accV[1]);
    accV[2] = fmaf(xv, c.z, accV[2]);
    accV[3] = fmaf(xv, c.w, accV[3]);
  }
}

// V2 quarter: 8 cols, 8 FMA per k
__device__ __forceinline__ void q_v2(const float (&hr)[32], int koff,
                                     const float* __restrict__ v2, float (&a2)[8])
{
  #pragma unroll
  for (int k = 0; k < 32; ++k) {
    const int kk = koff + k;
    float hv = hr[k];
    float4 a = *(const float4*)(v2 + kk*128);
    float4 b = *(const float4*)(v2 + kk*128 + 4);
    a2[0] = fmaf(hv, a.x, a2[0]);
    a2[1] = fmaf(hv, a.y, a2[1]);
    a2[2] = fmaf(hv, a.z, a2[2]);
    a2[3] = fmaf(hv, a.w, a2[3]);
    a2[4] = fmaf(hv, b.x, a2[4]);
    a2[5] = fmaf(hv, b.y, a2[5]);
    a2[6] = fmaf(hv, b.z, a2[6]);
    a2[7] = fmaf(hv, b.w, a2[7]);
  }
}

// L2 quarter: 16 cols, 16 FMA per k
__device__ __forceinline__ void q_l2(const float (&hr)[32], int koff,
                                     const float* __restrict__ w2, float (&a3)[16])
{
  #pragma unroll
  for (int k = 0; k < 32; ++k) {
    const int kk = koff + k;
    float hh = hr[k];
    float4 a = *(const float4*)(w2 + kk*256);
    float4 b = *(const float4*)(w2 + kk*256 + 4);
    float4 c = *(const float4*)(w2 + kk*256 + 8);
    float4 d = *(const float4*)(w2 + kk*256 + 12);
    a3[0]  = fmaf(hh, a.x, a3[0]);
    a3[1]  = fmaf(hh, a.y, a3[1]);
    a3[2]  = fmaf(hh, a.z, a3[2]);
    a3[3]  = fmaf(hh, a.w, a3[3]);
    a3[4]  = fmaf(hh, b.x, a3[4]);
    a3[5]  = fmaf(hh, b.y, a3[5]);
    a3[6]  = fmaf(hh, b.z, a3[6]);
    a3[7]  = fmaf(hh, b.w, a3[7]);
    a3[8]  = fmaf(hh, c.x, a3[8]);
    a3[9]  = fmaf(hh, c.y, a3[9]);
    a3[10] = fmaf(hh, c.z, a3[10]);
    a3[11] = fmaf(hh, c.w, a3[11]);
    a3[12] = fmaf(hh, d.x, a3[12]);
    a3[13] = fmaf(hh, d.y, a3[13]);
    a3[14] = fmaf(hh, d.z, a3[14]);
    a3[15] = fmaf(hh, d.w, a3[15]);
  }
}

// ---------------------------------------------------------------------------
// Fully fused. 64 rows/block (lane = row), 1024 threads, 16 waves = 16
// wave-uniform column slices (scalar-cache weight loads). Activations live
// in LDS TRANSPOSED [k][row] (stride 65): bulk reg-fills (32 ds_read_b32,
// conflict-free, one wait) keep the FMA loops pure s_load + v_fma.
// ---------------------------------------------------------------------------
__global__ __launch_bounds__(1024, 4) void fused_kernel(
    const float* __restrict__ x,
    const float* __restrict__ cb1, const float* __restrict__ cb2, const float* __restrict__ cb3,
    const float* __restrict__ wb1, const float* __restrict__ wb2, const float* __restrict__ wb3,
    const float* __restrict__ ws, float* __restrict__ out)
{
  __shared__ float u0[128 * 65];   // xT [128][64]p65; later hvT [64][64]p65
  __shared__ float h1T[128 * 65];  // h1T [128][64]p65
  __shared__ float vbuf[640];      // logit partials -> softmax w [64][10]
  __shared__ float cpbuf[1280];    // cp partials -> wm [64][20]

  const int tid = threadIdx.x;
  const int l   = tid & 63;                                   // lane = row
  const int w   = __builtin_amdgcn_readfirstlane(tid >> 6);   // 0..15
  const int b0  = blockIdx.x * 64;

  const float* CW1T = ws + OFF_CW1T;
  const float* CW2T = ws + OFF_CW2T;
  const float* CW3T = ws + OFF_CW3T;
  const float* WW1T = ws + OFF_WW1T;
  const float* WW2T = ws + OFF_WW2T;
  const float* WW3T = ws + OFF_WW3T;

  // ---- P0: stage x [64][128] -> u0 transposed [k][row] (stride 65)
  {
    const float4* xg = (const float4*)(x + (size_t)b0 * 128);
    #pragma unroll
    for (int i = tid; i < 2048; i += 1024) {
      float4 v = xg[i];
      int rr = i >> 5, kk = (i & 31) << 2;
      u0[(kk + 0) * 65 + rr] = v.x;
      u0[(kk + 1) * 65 + rr] = v.y;
      u0[(kk + 2) * 65 + rr] = v.z;
      u0[(kk + 3) * 65 + rr] = v.w;
    }
    if (tid < 640) vbuf[tid] = 0.f;
    for (int i = tid; i < 1280; i += 1024) cpbuf[i] = 0.f;
  }
  __syncthreads();   // B1

  // ---- P1: L1 (8 cols @ 8w) + V1 (4 cols @ 4w), K=128, x in reg quarters
  float accL[8], accV[4];
  {
    #pragma unroll
    for (int j = 0; j < 8; ++j) accL[j] = cb1[8*w + j];
    #pragma unroll
    for (int j = 0; j < 4; ++j) accV[j] = wb1[4*w + j];
    const float* w1 = CW1T + 8*w;
    const float* v1 = WW1T + 4*w;
    float xr[32];
    fill32(xr, u0, 0,  l); q_l1v1(xr, 0,  w1, v1, accL, accV);
    fill32(xr, u0, 32, l); q_l1v1(xr, 32, w1, v1, accL, accV);
    fill32(xr, u0, 64, l); q_l1v1(xr, 64, w1, v1, accL, accV);
    fill32(xr, u0, 96, l);
    __syncthreads();   // B1b: last xT read done -> u0 reusable as hvT
    q_l1v1(xr, 96, w1, v1, accL, accV);
  }
  // epilogue: h1 -> h1T, hv1 -> u0 (both transposed, stride 65)
  {
    #pragma unroll
    for (int j = 0; j < 8; ++j) h1T[(8*w + j) * 65 + l] = fmaxf(accL[j], 0.f);
    #pragma unroll
    for (int j = 0; j < 4; ++j) u0[(4*w + j) * 65 + l] = fmaxf(accV[j], 0.f);
  }
  __syncthreads();   // B2: h1T + hvT ready

  // ---- P2: V2 (8 cols @ 8w, K=64) + fused V3 -> logit partials -> vbuf
  {
    float a2[8];
    #pragma unroll
    for (int j = 0; j < 8; ++j) a2[j] = wb2[8*w + j];
    const float* v2 = WW2T + 8*w;
    float hr[32];
    fill32(hr, u0, 0,  l); q_v2(hr, 0,  v2, a2);
    fill32(hr, u0, 32, l); q_v2(hr, 32, v2, a2);

    float vp[10];
    #pragma unroll
    for (int j = 0; j < 10; ++j) vp[j] = 0.f;
    #pragma unroll
    for (int c = 0; c < 8; ++c) {
      float h = fmaxf(a2[c], 0.f);
      const float* t = WW3T + (8*w + c) * 10;
      #pragma unroll
      for (int j = 0; j < 10; j += 2) {
        float2 tv = *(const float2*)(t + j);
        vp[j]   = fmaf(h, tv.x, vp[j]);
        vp[j+1] = fmaf(h, tv.y, vp[j+1]);
      }
    }
    #pragma unroll
    for (int j = 0; j < 10; ++j) atomicAdd(vbuf + l*10 + j, vp[j]);
  }
  __syncthreads();   // B3

  // ---- P3: softmax (wave 0; in-place in vbuf). Other waves go on to P4.
  if (tid < 64) {
    float lg[10]; float m = -1e30f;
    #pragma unroll
    for (int j = 0; j < 10; ++j) { lg[j] = vbuf[l*10 + j] + wb3[j]; m = fmaxf(m, lg[j]); }
    float s = 0.f;
    #pragma unroll
    for (int j = 0; j < 10; ++j) { float e = expf(lg[j] - m); lg[j] = e; s += e; }
    float inv = __builtin_amdgcn_rcpf(s);
    #pragma unroll
    for (int j = 0; j < 10; ++j) vbuf[l*10 + j] = lg[j] * inv;
  }

  // ---- P4: L2 (16 cols @ 16w, K=128) + fused L3 -> cp partials -> cpbuf
  {
    float a3[16];
    #pragma unroll
    for (int j = 0; j < 16; ++j) a3[j] = cb2[16*w + j];
    const float* w2 = CW2T + 16*w;
    float hr[32];
    fill32(hr, h1T, 0,  l); q_l2(hr, 0,  w2, a3);
    fill32(hr, h1T, 32, l); q_l2(hr, 32, w2, a3);
    fill32(hr, h1T, 64, l); q_l2(hr, 64, w2, a3);
    fill32(hr, h1T, 96, l); q_l2(hr, 96, w2, a3);

    float cp[20];
    #pragma unroll
    for (int j = 0; j < 20; ++j) cp[j] = 0.f;
    #pragma unroll
    for (int c = 0; c < 16; ++c) {
      float h = fmaxf(a3[c], 0.f);
      const float* t = CW3T + (16*w + c) * 20;
      #pragma unroll
      for (int j = 0; j < 20; j += 4) {
        float4 tv = *(const float4*)(t + j);
        cp[j]   = fmaf(h, tv.x, cp[j]);
        cp[j+1] = fmaf(h, tv.y, cp[j+1]);
        cp[j+2] = fmaf(h, tv.z, cp[j+2]);
        cp[j+3] = fmaf(h, tv.w, cp[j+3]);
      }
    }
    #pragma unroll
    for (int j = 0; j < 20; ++j) atomicAdd(cpbuf + l*20 + j, cp[j]);
  }
  __syncthreads();   // B4: cp atomics + softmax done

  // ---- P5: wm = w * cp_mean (wave 0; wm into cpbuf[r][0..10))
  if (tid < 64) {
    #pragma unroll
    for (int p = 0; p < 10; ++p) {
      float s0 = cpbuf[l*20 + 2*p]     + cb3[2*p];
      float s1 = cpbuf[l*20 + 2*p + 1] + cb3[2*p + 1];
      float cm = 0.5f * (tanhf(s0) + tanhf(s1));
      cpbuf[l*20 + p] = vbuf[l*10 + p] * cm;
    }
  }
  __syncthreads();   // B5

  // ---- P6: combine + output. thread = 2 consecutive f-cols x 32 rows.
  {
    const float* BAS = ws + OFF_BASIS;
    const int fpair = tid & 511;
    const int rbase = (tid >> 9) * 32;
    const int f0 = fpair * 2;

    float bas[20];
    {
      const float4* bp = (const float4*)(BAS + f0 * 10);
      #pragma unroll
      for (int i = 0; i < 5; ++i) {
        float4 v = bp[i];
        bas[4*i+0] = v.x; bas[4*i+1] = v.y; bas[4*i+2] = v.z; bas[4*i+3] = v.w;
      }
    }
    for (int r = 0; r < 32; ++r) {
      int rr = rbase + r;
      float wv[10], wm[10];
      #pragma unroll
      for (int p = 0; p < 10; p += 2) {
        float2 a = *(const float2*)(vbuf + rr*10 + p);
        wv[p] = a.x; wv[p+1] = a.y;
        float2 b = *(const float2*)(cpbuf + rr*20 + p);
        wm[p] = b.x; wm[p+1] = b.y;
      }
      float n0 = 0.f, d0 = EPS, n1 = 0.f, d1 = EPS;
      #pragma unroll
      for (int p = 0; p < 10; ++p) {
        n0 = fmaf(bas[p],      wm[p], n0);
        d0 = fmaf(bas[p],      wv[p], d0);
        n1 = fmaf(bas[10 + p], wm[p], n1);
        d1 = fmaf(bas[10 + p], wv[p], d1);
      }
      float2 o;
      o.x = n0 * __builtin_amdgcn_rcpf(d0);
      o.y = n1 * __builtin_amdgcn_rcpf(d1);
      *(float2*)(out + (size_t)(b0 + rr) * 1024 + f0) = o;
    }
  }
}

// ---------------------------------------------------------------------------
extern "C" void kernel_launch(void* const* d_in, const int* in_sizes, int n_in,
                              void* d_out, int out_size, void* d_ws, size_t ws_size,
                              hipStream_t stream)
{
  const float* x   = (const float*)d_in[0];
  const float* cw1 = (const float*)d_in[1];
  const float* cb1 = (const float*)d_in[2];
  const float* cw2 = (const float*)d_in[3];
  const float* cb2 = (const float*)d_in[4];
  const float* cw3 = (const float*)d_in[5];
  const float* cb3 = (const float*)d_in[6];
  const float* ww1 = (const float*)d_in[7];
  const float* wb1 = (const float*)d_in[8];
  const float* ww2 = (const float*)d_in[9];
  const float* wb2 = (const float*)d_in[10];
  const float* ww3 = (const float*)d_in[11];
  const float* wb3 = (const float*)d_in[12];
  float* ws  = (float*)d_ws;
  float* out = (float*)d_out;

  prep_kernel<<<285, 256, 0, stream>>>(cw1, cw2, cw3, ww1, ww2, ww3, ws);
  fused_kernel<<<256, 1024, 0, stream>>>(x, cb1, cb2, cb3, wb1, wb2, wb3, ws, out);
}

// Round 7
// 79.159 us; speedup vs baseline: 2.4820x; 1.6345x over previous
//
#include <hip/hip_runtime.h>
#include <math.h>

#define EPS 1e-8f

typedef __attribute__((ext_vector_type(8))) short bf16x8;
typedef __attribute__((ext_vector_type(4))) float f32x4;

// ---- ws layout (FLOAT units) ----
// B-fragments (bf16 hi/lo planes), per tile: 1024 bf16 = 512 floats.
#define OFF_F1    0        // L1  [nt=8][kt=4] tiles
#define OFF_FV1   16384    // V1  [4][4]
#define OFF_F2    24576    // L2  [16][4]
#define OFF_FV2   57344    // V2  [8][2]
#define OFF_W3T   65536    // [256][20] fp32 (k-major)
#define OFF_V3T   70656    // [128][10] fp32
#define OFF_BASIS 71936    // [1024][10] fp32

__device__ __forceinline__ unsigned short f2bf(float f){
  unsigned u = __float_as_uint(f);
  return (unsigned short)((u + 0x7fffu + ((u >> 16) & 1u)) >> 16);
}
__device__ __forceinline__ float bf2f(unsigned short h){
  return __uint_as_float(((unsigned)h) << 16);
}
// LDS A-frag slot swizzle (keeps frag-build writes and b128 reads conflict-lite)
__device__ __forceinline__ int fslot(int s, int kt){
  return s ^ kt ^ (((s >> 4) & 1) << 2);
}

// ---------------------------------------------------------------------------
// prep: build B-fragment hi/lo bf16 planes for L1/V1/L2/V2; transpose W3/V3
// to fp32 k-major; compute basis. B-frag tile (nt,kt), lane s, elem j holds
// W[nt*16+(s&15)][kt*32+8*(s>>4)+j]  (W is [N][K] row-major = original).
// ---------------------------------------------------------------------------
__global__ __launch_bounds__(256) void prep_kernel(
    const float* __restrict__ cw1, const float* __restrict__ cw2, const float* __restrict__ cw3,
    const float* __restrict__ ww1, const float* __restrict__ ww2, const float* __restrict__ ww3,
    float* __restrict__ ws)
{
  int id = blockIdx.x * 256 + threadIdx.x;
  unsigned short* wsU = (unsigned short*)ws;
  if (id < 8192) {
    int t = id >> 6, s = id & 63;
    const float* W; int K, tloc, dstF, ktm;
    if (t < 32)       { W = cw1; K = 128; tloc = t;       dstF = OFF_F1;  ktm = 3; }
    else if (t < 48)  { W = ww1; K = 128; tloc = t - 32;  dstF = OFF_FV1; ktm = 3; }
    else if (t < 112) { W = cw2; K = 128; tloc = t - 48;  dstF = OFF_F2;  ktm = 3; }
    else              { W = ww2; K = 64;  tloc = t - 112; dstF = OFF_FV2; ktm = 1; }
    int kt = tloc & ktm;
    int nt = (ktm == 3) ? (tloc >> 2) : (tloc >> 1);
    int row = nt * 16 + (s & 15);
    int kb  = kt * 32 + 8 * (s >> 4);
    const float* src = W + row * K + kb;
    bf16x8 hv, lv;
    #pragma unroll
    for (int j = 0; j < 8; ++j) {
      float v = src[j];
      unsigned short h = f2bf(v);
      hv[j] = (short)h;
      lv[j] = (short)f2bf(v - bf2f(h));
    }
    unsigned short* dst = wsU + dstF * 2 + tloc * 1024 + s * 8;
    *(bf16x8*)dst = hv;
    *(bf16x8*)(dst + 512) = lv;
    return;
  }
  id -= 8192;
  if (id < 5120) { int k = id / 20, j = id % 20; ws[OFF_W3T + id] = cw3[j*256 + k]; return; }
  id -= 5120;
  if (id < 1280) { int k = id / 10, j = id % 10; ws[OFF_V3T + id] = ww3[j*128 + k]; return; }
  id -= 1280;
  if (id < 1024) {
    int f = id;
    float tt = (float)f * (1.0f / 1023.0f);
    float v[10]; float s = 0.f;
    #pragma unroll
    for (int p = 0; p < 10; ++p) {
      float d = tt - (float)p * (1.0f / 9.0f);
      float e = expf(-d * d * 50.0f);
      v[p] = e; s += e;
    }
    float inv = 1.0f / (s + EPS);
    #pragma unroll
    for (int p = 0; p < 10; ++p) ws[OFF_BASIS + f*10 + p] = v[p] * inv;
  }
}

// ---------------------------------------------------------------------------
// Fused MFMA kernel. 32 rows/block, 512 threads (8 waves), grid 512
// (2 blocks/CU). bf16x3: acc = Ah*Bh (chain A) + Ah*Bl + Al*Bh (chain B).
// Fragment layouts (16x16x32): A: row=l&15, k=8*(l>>4)+j; B: col=l&15,
// same k; D: col=l&15, row=4*(l>>4)+reg.
// ---------------------------------------------------------------------------
__global__ __launch_bounds__(512, 4) void fused_kernel(
    const float* __restrict__ x,
    const float* __restrict__ cb1, const float* __restrict__ cb2, const float* __restrict__ cb3,
    const float* __restrict__ wb1, const float* __restrict__ wb2, const float* __restrict__ wb3,
    const float* __restrict__ ws, float* __restrict__ out)
{
  __shared__ float pool[12672];          // h2T [256][33] @0, hv2T [128][33] @8448
  __shared__ unsigned short H1A[8192];   // h1 A-frags [mt2][kt4] x 1024
  __shared__ unsigned short HV1A[4096];  // hv1 A-frags [mt2][kt2] x 1024
  __shared__ float vbuf[320];            // logits -> softmax w [32][10]
  __shared__ float cpbuf[640];           // cp sums -> wm [32][20]

  const int tid = threadIdx.x;
  const int l   = tid & 63;
  const int w   = tid >> 6;     // 0..7
  const int g   = l >> 4;       // 0..3
  const int c16 = l & 15;
  const int b0  = blockIdx.x * 32;

  unsigned short* XA = (unsigned short*)pool;  // x A-frags [mt2][kt4] x 1024 (dies at B2)
  float* h2T  = pool;                          // live after B2
  float* hv2T = pool + 8448;
  const unsigned short* wsU = (const unsigned short*)ws;

  // ---- P0: load x, split hi/lo, write XA frags; zero reduce buffers
  {
    int r = tid >> 4, k8 = tid & 15;           // elem block: row r, k = k8*8..+8
    const float4* xg = (const float4*)(x + (size_t)(b0 + r) * 128 + k8 * 8);
    float4 v0 = xg[0], v1 = xg[1];
    float xv[8] = {v0.x, v0.y, v0.z, v0.w, v1.x, v1.y, v1.z, v1.w};
    bf16x8 hv, lv;
    #pragma unroll
    for (int j = 0; j < 8; ++j) {
      unsigned short h = f2bf(xv[j]);
      hv[j] = (short)h;
      lv[j] = (short)f2bf(xv[j] - bf2f(h));
    }
    int kt = k8 >> 2;
    int tile = (r >> 4) * 4 + kt;
    int s = (r & 15) + 16 * (k8 & 3);
    unsigned short* dst = XA + tile * 1024 + fslot(s, kt) * 8;
    *(bf16x8*)dst = hv;
    *(bf16x8*)(dst + 512) = lv;
    if (tid < 320) vbuf[tid] = 0.f;
    cpbuf[tid] = 0.f;
    if (tid < 128) cpbuf[512 + tid] = 0.f;
  }
  __syncthreads();   // B1

  // ---- P1: V1 (hv1 = relu(x@ww1^T+b)), 1 tile/wave -> HV1A frags
  {
    int mt = w >> 2, nt = w & 3;
    float b = wb1[nt * 16 + c16];
    f32x4 aA = {b, b, b, b};
    f32x4 aB = {0.f, 0.f, 0.f, 0.f};
    #pragma unroll
    for (int kt = 0; kt < 4; ++kt) {
      const unsigned short* ap = XA + (mt * 4 + kt) * 1024 + fslot(l, kt) * 8;
      bf16x8 ah = *(const bf16x8*)ap;
      bf16x8 al = *(const bf16x8*)(ap + 512);
      const unsigned short* bp = wsU + OFF_FV1 * 2 + (nt * 4 + kt) * 1024 + l * 8;
      bf16x8 bh = *(const bf16x8*)bp;
      bf16x8 bl = *(const bf16x8*)(bp + 512);
      aA = __builtin_amdgcn_mfma_f32_16x16x32_bf16(ah, bh, aA, 0, 0, 0);
      aB = __builtin_amdgcn_mfma_f32_16x16x32_bf16(ah, bl, aB, 0, 0, 0);
      aB = __builtin_amdgcn_mfma_f32_16x16x32_bf16(al, bh, aB, 0, 0, 0);
    }
    int kt2 = nt >> 1;
    int sb = 16 * ((2 * nt + (c16 >> 3)) & 3);
    int j = c16 & 7;
    unsigned short* tb = HV1A + (mt * 2 + kt2) * 1024;
    #pragma unroll
    for (int i = 0; i < 4; ++i) {
      float v = fmaxf(aA[i] + aB[i], 0.f);
      int idx = fslot(4 * g + i + sb, kt2) * 8 + j;
      unsigned short h = f2bf(v);
      tb[idx] = h;
      tb[512 + idx] = f2bf(v - bf2f(h));
    }
  }

  // ---- P2: L1 (h1), 2 tiles/wave -> H1A frags
  {
    int mt = w >> 2;
    int nt0 = (w & 3) * 2, nt1 = nt0 + 1;
    float b0f = cb1[nt0 * 16 + c16], b1f = cb1[nt1 * 16 + c16];
    f32x4 aA0 = {b0f, b0f, b0f, b0f}, aB0 = {0.f, 0.f, 0.f, 0.f};
    f32x4 aA1 = {b1f, b1f, b1f, b1f}, aB1 = {0.f, 0.f, 0.f, 0.f};
    #pragma unroll
    for (int kt = 0; kt < 4; ++kt) {
      const unsigned short* ap = XA + (mt * 4 + kt) * 1024 + fslot(l, kt) * 8;
      bf16x8 ah = *(const bf16x8*)ap;
      bf16x8 al = *(const bf16x8*)(ap + 512);
      const unsigned short* bp0 = wsU + OFF_F1 * 2 + (nt0 * 4 + kt) * 1024 + l * 8;
      const unsigned short* bp1 = wsU + OFF_F1 * 2 + (nt1 * 4 + kt) * 1024 + l * 8;
      bf16x8 b0h = *(const bf16x8*)bp0, b0l = *(const bf16x8*)(bp0 + 512);
      bf16x8 b1h = *(const bf16x8*)bp1, b1l = *(const bf16x8*)(bp1 + 512);
      aA0 = __builtin_amdgcn_mfma_f32_16x16x32_bf16(ah, b0h, aA0, 0, 0, 0);
      aB0 = __builtin_amdgcn_mfma_f32_16x16x32_bf16(ah, b0l, aB0, 0, 0, 0);
      aB0 = __builtin_amdgcn_mfma_f32_16x16x32_bf16(al, b0h, aB0, 0, 0, 0);
      aA1 = __builtin_amdgcn_mfma_f32_16x16x32_bf16(ah, b1h, aA1, 0, 0, 0);
      aB1 = __builtin_amdgcn_mfma_f32_16x16x32_bf16(ah, b1l, aB1, 0, 0, 0);
      aB1 = __builtin_amdgcn_mfma_f32_16x16x32_bf16(al, b1h, aB1, 0, 0, 0);
    }
    #pragma unroll
    for (int t2 = 0; t2 < 2; ++t2) {
      int nt = nt0 + t2;
      int kt2 = nt >> 1;
      int sb = 16 * ((2 * nt + (c16 >> 3)) & 3);
      int j = c16 & 7;
      unsigned short* tb = H1A + (mt * 4 + kt2) * 1024;
      #pragma unroll
      for (int i = 0; i < 4; ++i) {
        float v = t2 ? fmaxf(aA1[i] + aB1[i], 0.f) : fmaxf(aA0[i] + aB0[i], 0.f);
        int idx = fslot(4 * g + i + sb, kt2) * 8 + j;
        unsigned short h = f2bf(v);
        tb[idx] = h;
        tb[512 + idx] = f2bf(v - bf2f(h));
      }
    }
  }
  __syncthreads();   // B2: XA dead; H1A/HV1A ready

  // ---- P3: V2 (hv2 = relu(hv1@ww2^T+b)), 2 tiles/wave -> hv2T fp32
  {
    int mt = w >> 2;
    int nt0 = (w & 3) * 2, nt1 = nt0 + 1;
    float b0f = wb2[nt0 * 16 + c16], b1f = wb2[nt1 * 16 + c16];
    f32x4 aA0 = {b0f, b0f, b0f, b0f}, aB0 = {0.f, 0.f, 0.f, 0.f};
    f32x4 aA1 = {b1f, b1f, b1f, b1f}, aB1 = {0.f, 0.f, 0.f, 0.f};
    #pragma unroll
    for (int kt = 0; kt < 2; ++kt) {
      const unsigned short* ap = HV1A + (mt * 2 + kt) * 1024 + fslot(l, kt) * 8;
      bf16x8 ah = *(const bf16x8*)ap;
      bf16x8 al = *(const bf16x8*)(ap + 512);
      const unsigned short* bp0 = wsU + OFF_FV2 * 2 + (nt0 * 2 + kt) * 1024 + l * 8;
      const unsigned short* bp1 = wsU + OFF_FV2 * 2 + (nt1 * 2 + kt) * 1024 + l * 8;
      bf16x8 b0h = *(const bf16x8*)bp0, b0l = *(const bf16x8*)(bp0 + 512);
      bf16x8 b1h = *(const bf16x8*)bp1, b1l = *(const bf16x8*)(bp1 + 512);
      aA0 = __builtin_amdgcn_mfma_f32_16x16x32_bf16(ah, b0h, aA0, 0, 0, 0);
      aB0 = __builtin_amdgcn_mfma_f32_16x16x32_bf16(ah, b0l, aB0, 0, 0, 0);
      aB0 = __builtin_amdgcn_mfma_f32_16x16x32_bf16(al, b0h, aB0, 0, 0, 0);
      aA1 = __builtin_amdgcn_mfma_f32_16x16x32_bf16(ah, b1h, aA1, 0, 0, 0);
      aB1 = __builtin_amdgcn_mfma_f32_16x16x32_bf16(ah, b1l, aB1, 0, 0, 0);
      aB1 = __builtin_amdgcn_mfma_f32_16x16x32_bf16(al, b1h, aB1, 0, 0, 0);
    }
    int r0 = mt * 16 + 4 * g;
    #pragma unroll
    for (int i = 0; i < 4; ++i) {
      hv2T[(nt0 * 16 + c16) * 33 + r0 + i] = fmaxf(aA0[i] + aB0[i], 0.f);
      hv2T[(nt1 * 16 + c16) * 33 + r0 + i] = fmaxf(aA1[i] + aB1[i], 0.f);
    }
  }

  // ---- P4: L2 (h2), 4 tiles/wave (2 pairs) -> h2T fp32
  {
    int mt = w >> 2;
    #pragma unroll
    for (int pp = 0; pp < 2; ++pp) {
      int nt0 = (w & 3) * 4 + pp * 2, nt1 = nt0 + 1;
      float b0f = cb2[nt0 * 16 + c16], b1f = cb2[nt1 * 16 + c16];
      f32x4 aA0 = {b0f, b0f, b0f, b0f}, aB0 = {0.f, 0.f, 0.f, 0.f};
      f32x4 aA1 = {b1f, b1f, b1f, b1f}, aB1 = {0.f, 0.f, 0.f, 0.f};
      #pragma unroll
      for (int kt = 0; kt < 4; ++kt) {
        const unsigned short* ap = H1A + (mt * 4 + kt) * 1024 + fslot(l, kt) * 8;
        bf16x8 ah = *(const bf16x8*)ap;
        bf16x8 al = *(const bf16x8*)(ap + 512);
        const unsigned short* bp0 = wsU + OFF_F2 * 2 + (nt0 * 4 + kt) * 1024 + l * 8;
        const unsigned short* bp1 = wsU + OFF_F2 * 2 + (nt1 * 4 + kt) * 1024 + l * 8;
        bf16x8 b0h = *(const bf16x8*)bp0, b0l = *(const bf16x8*)(bp0 + 512);
        bf16x8 b1h = *(const bf16x8*)bp1, b1l = *(const bf16x8*)(bp1 + 512);
        aA0 = __builtin_amdgcn_mfma_f32_16x16x32_bf16(ah, b0h, aA0, 0, 0, 0);
        aB0 = __builtin_amdgcn_mfma_f32_16x16x32_bf16(ah, b0l, aB0, 0, 0, 0);
        aB0 = __builtin_amdgcn_mfma_f32_16x16x32_bf16(al, b0h, aB0, 0, 0, 0);
        aA1 = __builtin_amdgcn_mfma_f32_16x16x32_bf16(ah, b1h, aA1, 0, 0, 0);
        aB1 = __builtin_amdgcn_mfma_f32_16x16x32_bf16(ah, b1l, aB1, 0, 0, 0);
        aB1 = __builtin_amdgcn_mfma_f32_16x16x32_bf16(al, b1h, aB1, 0, 0, 0);
      }
      int r0 = mt * 16 + 4 * g;
      #pragma unroll
      for (int i = 0; i < 4; ++i) {
        h2T[(nt0 * 16 + c16) * 33 + r0 + i] = fmaxf(aA0[i] + aB0[i], 0.f);
        h2T[(nt1 * 16 + c16) * 33 + r0 + i] = fmaxf(aA1[i] + aB1[i], 0.f);
      }
    }
  }
  __syncthreads();   // B3: h2T/hv2T ready

  // ---- P5: V3 logits partials (16 slices x 8 cols) -> vbuf atomics
  {
    const int half = l >> 5, r = l & 31;
    const int cb = (w * 2 + half) * 8;
    const float* V3T = ws + OFF_V3T;
    float vp[10];
    #pragma unroll
    for (int j = 0; j < 10; ++j) vp[j] = 0.f;
    #pragma unroll
    for (int cc = 0; cc < 8; ++cc) {
      int c = cb + cc;
      float h = hv2T[c * 33 + r];
      const float* t = V3T + c * 10;
      #pragma unroll
      for (int j = 0; j < 10; j += 2) {
        float2 tv = *(const float2*)(t + j);
        vp[j]   = fmaf(h, tv.x, vp[j]);
        vp[j+1] = fmaf(h, tv.y, vp[j+1]);
      }
    }
    #pragma unroll
    for (int j = 0; j < 10; ++j) atomicAdd(vbuf + r * 10 + j, vp[j]);
  }
  __syncthreads();   // B4

  // ---- P6: softmax (tid<32, one row each)
  if (tid < 32) {
    float lg[10]; float m = -1e30f;
    #pragma unroll
    for (int j = 0; j < 10; ++j) { lg[j] = vbuf[tid*10 + j] + wb3[j]; m = fmaxf(m, lg[j]); }
    float s = 0.f;
    #pragma unroll
    for (int j = 0; j < 10; ++j) { float e = expf(lg[j] - m); lg[j] = e; s += e; }
    float inv = __builtin_amdgcn_rcpf(s);
    #pragma unroll
    for (int j = 0; j < 10; ++j) vbuf[tid*10 + j] = lg[j] * inv;
  }

  // ---- P7: L3 cp partials (16 slices x 16 cols) -> cpbuf atomics
  {
    const int half = l >> 5, r = l & 31;
    const int cb = (w * 2 + half) * 16;
    const float* W3T = ws + OFF_W3T;
    float cp[20];
    #pragma unroll
    for (int j = 0; j < 20; ++j) cp[j] = 0.f;
    #pragma unroll
    for (int cc = 0; cc < 16; ++cc) {
      int c = cb + cc;
      float h = h2T[c * 33 + r];
      const float* t = W3T + c * 20;
      #pragma unroll
      for (int j = 0; j < 20; j += 4) {
        float4 tv = *(const float4*)(t + j);
        cp[j]   = fmaf(h, tv.x, cp[j]);
        cp[j+1] = fmaf(h, tv.y, cp[j+1]);
        cp[j+2] = fmaf(h, tv.z, cp[j+2]);
        cp[j+3] = fmaf(h, tv.w, cp[j+3]);
      }
    }
    #pragma unroll
    for (int j = 0; j < 20; ++j) atomicAdd(cpbuf + r * 20 + j, cp[j]);
  }
  __syncthreads();   // B5

  // ---- P8: wm = w * cp_mean (tid<32)
  if (tid < 32) {
    #pragma unroll
    for (int p = 0; p < 10; ++p) {
      float s0 = cpbuf[tid*20 + 2*p]     + cb3[2*p];
      float s1 = cpbuf[tid*20 + 2*p + 1] + cb3[2*p + 1];
      float cm = 0.5f * (tanhf(s0) + tanhf(s1));
      cpbuf[tid*20 + p] = vbuf[tid*10 + p] * cm;
    }
  }
  __syncthreads();   // B6

  // ---- P9: combine + output. thread = 2 consecutive f-cols x 32 rows.
  {
    const float* BAS = ws + OFF_BASIS;
    const int f0 = tid * 2;
    float bas[20];
    {
      const float4* bp = (const float4*)(BAS + f0 * 10);
      #pragma unroll
      for (int i = 0; i < 5; ++i) {
        float4 v = bp[i];
        bas[4*i+0] = v.x; bas[4*i+1] = v.y; bas[4*i+2] = v.z; bas[4*i+3] = v.w;
      }
    }
    for (int rr = 0; rr < 32; ++rr) {
      float wv[10], wm[10];
      #pragma unroll
      for (int p = 0; p < 10; p += 2) {
        float2 a = *(const float2*)(vbuf + rr*10 + p);
        wv[p] = a.x; wv[p+1] = a.y;
        float2 b = *(const float2*)(cpbuf + rr*20 + p);
        wm[p] = b.x; wm[p+1] = b.y;
      }
      float n0 = 0.f, d0 = EPS, n1 = 0.f, d1 = EPS;
      #pragma unroll
      for (int p = 0; p < 10; ++p) {
        n0 = fmaf(bas[p],      wm[p], n0);
        d0 = fmaf(bas[p],      wv[p], d0);
        n1 = fmaf(bas[10 + p], wm[p], n1);
        d1 = fmaf(bas[10 + p], wv[p], d1);
      }
      float2 o;
      o.x = n0 * __builtin_amdgcn_rcpf(d0);
      o.y = n1 * __builtin_amdgcn_rcpf(d1);
      *(float2*)(out + (size_t)(b0 + rr) * 1024 + f0) = o;
    }
  }
}

// ---------------------------------------------------------------------------
extern "C" void kernel_launch(void* const* d_in, const int* in_sizes, int n_in,
                              void* d_out, int out_size, void* d_ws, size_t ws_size,
                              hipStream_t stream)
{
  const float* x   = (const float*)d_in[0];
  const float* cw1 = (const float*)d_in[1];
  const float* cb1 = (const float*)d_in[2];
  const float* cw2 = (const float*)d_in[3];
  const float* cb2 = (const float*)d_in[4];
  const float* cw3 = (const float*)d_in[5];
  const float* cb3 = (const float*)d_in[6];
  const float* ww1 = (const float*)d_in[7];
  const float* wb1 = (const float*)d_in[8];
  const float* ww2 = (const float*)d_in[9];
  const float* wb2 = (const float*)d_in[10];
  const float* ww3 = (const float*)d_in[11];
  const float* wb3 = (const float*)d_in[12];
  float* ws  = (float*)d_ws;
  float* out = (float*)d_out;

  prep_kernel<<<61, 256, 0, stream>>>(cw1, cw2, cw3, ww1, ww2, ww3, ws);
  fused_kernel<<<512, 512, 0, stream>>>(x, cb1, cb2, cb3, wb1, wb2, wb3, ws, out);
}

// Round 8
// 39.207 us; speedup vs baseline: 5.0112x; 2.0190x over previous
//
#include <hip/hip_runtime.h>
#include <math.h>

#define EPS 1e-8f

typedef __attribute__((ext_vector_type(8))) short bf16x8;
typedef __attribute__((ext_vector_type(4))) float f32x4;

// ---- ws layout (FLOAT units). B-frag tile = 1024 bf16 (hi 512 + lo 512) = 512 floats.
#define OFF_F1    0        // L1  cw1 [8 nt][4 kt]
#define OFF_FV1   16384    // V1  ww1 [4][4]
#define OFF_F2    24576    // L2  cw2 [16][4]
#define OFF_FV2   57344    // V2  ww2 [8][2]
#define OFF_F3    65536    // L3  cw3 [2][8]  (20 rows padded to 32)
#define OFF_FV3   73728    // V3  ww3 [1][4]  (10 rows padded to 16)
#define OFF_BASIS 75776    // [1024][10] fp32

__device__ __forceinline__ unsigned short f2bf(float f){
  unsigned u = __float_as_uint(f);
  return (unsigned short)((u + 0x7fffu + ((u >> 16) & 1u)) >> 16);
}
__device__ __forceinline__ float bf2f(unsigned short h){
  return __uint_as_float(((unsigned)h) << 16);
}
__device__ __forceinline__ int fslot(int s, int kt){
  return s ^ kt ^ (((s >> 4) & 1) << 2);
}

// ---------------------------------------------------------------------------
// prep: B-fragment hi/lo bf16 planes for all six layers + basis.
// Tile (nt,kt), lane s, elem j holds W[nt*16+(s&15)][kt*32+8*(s>>4)+j], 0-pad
// rows >= N.
// ---------------------------------------------------------------------------
__global__ __launch_bounds__(256) void prep_kernel(
    const float* __restrict__ cw1, const float* __restrict__ cw2, const float* __restrict__ cw3,
    const float* __restrict__ ww1, const float* __restrict__ ww2, const float* __restrict__ ww3,
    float* __restrict__ ws)
{
  int id = blockIdx.x * 256 + threadIdx.x;
  unsigned short* wsU = (unsigned short*)ws;
  if (id < 9472) {
    int t = id >> 6, s = id & 63;
    const float* W; int K, N, tloc, dstF, ktbits;
    if (t < 32)       { W = cw1; K = 128; N = 128; tloc = t;       dstF = OFF_F1;  ktbits = 2; }
    else if (t < 48)  { W = ww1; K = 128; N = 64;  tloc = t - 32;  dstF = OFF_FV1; ktbits = 2; }
    else if (t < 112) { W = cw2; K = 128; N = 256; tloc = t - 48;  dstF = OFF_F2;  ktbits = 2; }
    else if (t < 128) { W = ww2; K = 64;  N = 128; tloc = t - 112; dstF = OFF_FV2; ktbits = 1; }
    else if (t < 144) { W = cw3; K = 256; N = 20;  tloc = t - 128; dstF = OFF_F3;  ktbits = 3; }
    else              { W = ww3; K = 128; N = 10;  tloc = t - 144; dstF = OFF_FV3; ktbits = 2; }
    int kt = tloc & ((1 << ktbits) - 1);
    int nt = tloc >> ktbits;
    int row = nt * 16 + (s & 15);
    int kb  = kt * 32 + 8 * (s >> 4);
    bf16x8 hv, lv;
    #pragma unroll
    for (int j = 0; j < 8; ++j) {
      float v = (row < N) ? W[row * K + kb + j] : 0.f;
      unsigned short h = f2bf(v);
      hv[j] = (short)h;
      lv[j] = (short)f2bf(v - bf2f(h));
    }
    unsigned short* dst = wsU + dstF * 2 + tloc * 1024 + s * 8;
    *(bf16x8*)dst = hv;
    *(bf16x8*)(dst + 512) = lv;
    return;
  }
  id -= 9472;
  if (id < 1024) {
    int f = id;
    float tt = (float)f * (1.0f / 1023.0f);
    float v[10]; float s = 0.f;
    #pragma unroll
    for (int p = 0; p < 10; ++p) {
      float d = tt - (float)p * (1.0f / 9.0f);
      float e = expf(-d * d * 50.0f);
      v[p] = e; s += e;
    }
    float inv = 1.0f / (s + EPS);
    #pragma unroll
    for (int p = 0; p < 10; ++p) ws[OFF_BASIS + f*10 + p] = v[p] * inv;
  }
}

#define MFMA __builtin_amdgcn_mfma_f32_16x16x32_bf16

// ---------------------------------------------------------------------------
// Fully fused, all-MFMA MLP (bf16x3) + softmax/tanh tail + combine.
// 32 rows/block, 512 threads (8 waves), grid 512 (2 blocks/CU).
// No LDS atomics: every layer's K-reduction happens inside MFMA; D-frag
// elements have unique owners. B-frags 1-deep rotated; kt0 issued pre-barrier.
// ---------------------------------------------------------------------------
__global__ __launch_bounds__(512, 4) void fused_kernel(
    const float* __restrict__ x,
    const float* __restrict__ cb1, const float* __restrict__ cb2, const float* __restrict__ cb3,
    const float* __restrict__ wb1, const float* __restrict__ wb2, const float* __restrict__ wb3,
    const float* __restrict__ ws, float* __restrict__ out)
{
  __shared__ unsigned short H2A[16384];   // h2 A-frags [2 mt][8 kt]; [0..8192) aliases XA
  __shared__ unsigned short H1A[8192];    // h1 A-frags [2 mt][4 kt]
  __shared__ unsigned short HV1A[4096];   // hv1 A-frags [2 mt][2 kt]
  __shared__ unsigned short HV2A[8192];   // hv2 A-frags [2 mt][4 kt]
  __shared__ float vbuf[320];             // logits -> softmax w [32][10]
  __shared__ float cpbuf[640];            // cp sums -> wm [32][20]

  const int tid = threadIdx.x;
  const int l   = tid & 63;
  const int w   = tid >> 6;     // 0..7
  const int g   = l >> 4;       // 0..3
  const int c16 = l & 15;
  const int b0  = blockIdx.x * 32;
  unsigned short* XA = H2A;     // x A-frags [2 mt][4 kt], dead after B1..B2 region
  const unsigned short* wsU = (const unsigned short*)ws;

  // ---- P0: load x, split hi/lo, write XA frags
  {
    int r = tid >> 4, k8 = tid & 15;
    const float4* xg = (const float4*)(x + (size_t)(b0 + r) * 128 + k8 * 8);
    float4 v0 = xg[0], v1 = xg[1];
    float xv[8] = {v0.x, v0.y, v0.z, v0.w, v1.x, v1.y, v1.z, v1.w};
    bf16x8 hv, lv;
    #pragma unroll
    for (int j = 0; j < 8; ++j) {
      unsigned short h = f2bf(xv[j]);
      hv[j] = (short)h;
      lv[j] = (short)f2bf(xv[j] - bf2f(h));
    }
    int kt = k8 >> 2;
    int tile = (r >> 4) * 4 + kt;
    int s = (r & 15) + 16 * (k8 & 3);
    unsigned short* dst = XA + tile * 1024 + fslot(s, kt) * 8;
    *(bf16x8*)dst = hv;
    *(bf16x8*)(dst + 512) = lv;
  }

  // P1P2 pointers + kt0 B-frag prefetch (global, legal before barrier)
  const int mt  = w >> 2;            // row tile 0..1
  const int ntv = w & 3;             // V1 col tile
  const int nt0 = (w & 3) * 2, nt1 = nt0 + 1;  // L1 col tiles
  const unsigned short* BV  = wsU + OFF_FV1*2 + (ntv*4)*1024 + l*8;
  const unsigned short* BL0 = wsU + OFF_F1*2  + (nt0*4)*1024 + l*8;
  const unsigned short* BL1 = wsU + OFF_F1*2  + (nt1*4)*1024 + l*8;
  bf16x8 nvh = *(const bf16x8*)BV;        bf16x8 nvl = *(const bf16x8*)(BV + 512);
  bf16x8 n0h = *(const bf16x8*)BL0;       bf16x8 n0l = *(const bf16x8*)(BL0 + 512);
  bf16x8 n1h = *(const bf16x8*)BL1;       bf16x8 n1l = *(const bf16x8*)(BL1 + 512);

  __syncthreads();   // B1: XA ready

  // ---- P1P2: V1 (1 tile) + L1 (2 tiles) fused over kt, B rotated
  {
    float bv  = wb1[ntv*16 + c16];
    float bl0 = cb1[nt0*16 + c16], bl1 = cb1[nt1*16 + c16];
    f32x4 aVA = {bv, bv, bv, bv},     aVB = {0.f, 0.f, 0.f, 0.f};
    f32x4 aL0A = {bl0, bl0, bl0, bl0}, aL0B = {0.f, 0.f, 0.f, 0.f};
    f32x4 aL1A = {bl1, bl1, bl1, bl1}, aL1B = {0.f, 0.f, 0.f, 0.f};
    #pragma unroll
    for (int kt = 0; kt < 4; ++kt) {
      bf16x8 vh = nvh, vl = nvl, b0h_ = n0h, b0l_ = n0l, b1h_ = n1h, b1l_ = n1l;
      if (kt < 3) {
        nvh = *(const bf16x8*)(BV  + (kt+1)*1024); nvl = *(const bf16x8*)(BV  + (kt+1)*1024 + 512);
        n0h = *(const bf16x8*)(BL0 + (kt+1)*1024); n0l = *(const bf16x8*)(BL0 + (kt+1)*1024 + 512);
        n1h = *(const bf16x8*)(BL1 + (kt+1)*1024); n1l = *(const bf16x8*)(BL1 + (kt+1)*1024 + 512);
      }
      const unsigned short* ap = XA + (mt*4 + kt) * 1024 + fslot(l, kt) * 8;
      bf16x8 ah = *(const bf16x8*)ap;
      bf16x8 al = *(const bf16x8*)(ap + 512);
      aVA = MFMA(ah, vh, aVA, 0,0,0);   aVB = MFMA(ah, vl, aVB, 0,0,0);   aVB = MFMA(al, vh, aVB, 0,0,0);
      aL0A = MFMA(ah, b0h_, aL0A, 0,0,0); aL0B = MFMA(ah, b0l_, aL0B, 0,0,0); aL0B = MFMA(al, b0h_, aL0B, 0,0,0);
      aL1A = MFMA(ah, b1h_, aL1A, 0,0,0); aL1B = MFMA(ah, b1l_, aL1B, 0,0,0); aL1B = MFMA(al, b1h_, aL1B, 0,0,0);
    }
    // V1 epilogue -> HV1A (hv1 width 64)
    {
      int kt2 = ntv >> 1;
      int sb = 16 * ((2*ntv + (c16 >> 3)) & 3);
      unsigned short* tb = HV1A + (mt*2 + kt2) * 1024;
      #pragma unroll
      for (int i = 0; i < 4; ++i) {
        float v = fmaxf(aVA[i] + aVB[i], 0.f);
        int idx = fslot(4*g + i + sb, kt2) * 8 + (c16 & 7);
        unsigned short h = f2bf(v);
        tb[idx] = h; tb[512 + idx] = f2bf(v - bf2f(h));
      }
    }
    // L1 epilogue -> H1A (h1 width 128)
    #pragma unroll
    for (int t2 = 0; t2 < 2; ++t2) {
      int nt = nt0 + t2;
      int kt2 = nt >> 1;
      int sb = 16 * ((2*nt + (c16 >> 3)) & 3);
      unsigned short* tb = H1A + (mt*4 + kt2) * 1024;
      #pragma unroll
      for (int i = 0; i < 4; ++i) {
        float v = t2 ? fmaxf(aL1A[i] + aL1B[i], 0.f) : fmaxf(aL0A[i] + aL0B[i], 0.f);
        int idx = fslot(4*g + i + sb, kt2) * 8 + (c16 & 7);
        unsigned short h = f2bf(v);
        tb[idx] = h; tb[512 + idx] = f2bf(v - bf2f(h));
      }
    }
  }

  // P3 B-frag preloads (V2: 2 tiles x 2 kt), issued before the barrier
  const int v0t = (w & 3) * 2, v1t = v0t + 1;   // hv2 col tiles 0..7
  const unsigned short* C0 = wsU + OFF_FV2*2 + (v0t*2)*1024 + l*8;
  const unsigned short* C1 = wsU + OFF_FV2*2 + (v1t*2)*1024 + l*8;
  bf16x8 c0h0 = *(const bf16x8*)C0;          bf16x8 c0l0 = *(const bf16x8*)(C0 + 512);
  bf16x8 c0h1 = *(const bf16x8*)(C0 + 1024); bf16x8 c0l1 = *(const bf16x8*)(C0 + 1536);
  bf16x8 c1h0 = *(const bf16x8*)C1;          bf16x8 c1l0 = *(const bf16x8*)(C1 + 512);
  bf16x8 c1h1 = *(const bf16x8*)(C1 + 1024); bf16x8 c1l1 = *(const bf16x8*)(C1 + 1536);

  __syncthreads();   // B2: H1A/HV1A ready, XA dead

  // ---- P3: V2 (2 tiles/wave, K=64) -> HV2A frags
  {
    float bb0 = wb2[v0t*16 + c16], bb1 = wb2[v1t*16 + c16];
    f32x4 a0A = {bb0, bb0, bb0, bb0}, a0B = {0.f, 0.f, 0.f, 0.f};
    f32x4 a1A = {bb1, bb1, bb1, bb1}, a1B = {0.f, 0.f, 0.f, 0.f};
    {
      const unsigned short* ap = HV1A + (mt*2 + 0) * 1024 + fslot(l, 0) * 8;
      bf16x8 ah = *(const bf16x8*)ap, al = *(const bf16x8*)(ap + 512);
      a0A = MFMA(ah, c0h0, a0A, 0,0,0); a0B = MFMA(ah, c0l0, a0B, 0,0,0); a0B = MFMA(al, c0h0, a0B, 0,0,0);
      a1A = MFMA(ah, c1h0, a1A, 0,0,0); a1B = MFMA(ah, c1l0, a1B, 0,0,0); a1B = MFMA(al, c1h0, a1B, 0,0,0);
    }
    {
      const unsigned short* ap = HV1A + (mt*2 + 1) * 1024 + fslot(l, 1) * 8;
      bf16x8 ah = *(const bf16x8*)ap, al = *(const bf16x8*)(ap + 512);
      a0A = MFMA(ah, c0h1, a0A, 0,0,0); a0B = MFMA(ah, c0l1, a0B, 0,0,0); a0B = MFMA(al, c0h1, a0B, 0,0,0);
      a1A = MFMA(ah, c1h1, a1A, 0,0,0); a1B = MFMA(ah, c1l1, a1B, 0,0,0); a1B = MFMA(al, c1h1, a1B, 0,0,0);
    }
    #pragma unroll
    for (int t2 = 0; t2 < 2; ++t2) {
      int nt = v0t + t2;
      int kt2 = nt >> 1;
      int sb = 16 * ((2*nt + (c16 >> 3)) & 3);
      unsigned short* tb = HV2A + (mt*4 + kt2) * 1024;
      #pragma unroll
      for (int i = 0; i < 4; ++i) {
        float v = t2 ? fmaxf(a1A[i] + a1B[i], 0.f) : fmaxf(a0A[i] + a0B[i], 0.f);
        int idx = fslot(4*g + i + sb, kt2) * 8 + (c16 & 7);
        unsigned short h = f2bf(v);
        tb[idx] = h; tb[512 + idx] = f2bf(v - bf2f(h));
      }
    }
  }

  // ---- P4: L2 (4 tiles/wave in 2 pairs, K=128) -> H2A frags, B rotated
  #pragma unroll
  for (int pp = 0; pp < 2; ++pp) {
    const int m0 = (w & 3) * 4 + pp * 2, m1 = m0 + 1;   // h2 col tiles 0..15
    const unsigned short* D0 = wsU + OFF_F2*2 + (m0*4)*1024 + l*8;
    const unsigned short* D1 = wsU + OFF_F2*2 + (m1*4)*1024 + l*8;
    bf16x8 nd0h = *(const bf16x8*)D0, nd0l = *(const bf16x8*)(D0 + 512);
    bf16x8 nd1h = *(const bf16x8*)D1, nd1l = *(const bf16x8*)(D1 + 512);
    float bb0 = cb2[m0*16 + c16], bb1 = cb2[m1*16 + c16];
    f32x4 a0A = {bb0, bb0, bb0, bb0}, a0B = {0.f, 0.f, 0.f, 0.f};
    f32x4 a1A = {bb1, bb1, bb1, bb1}, a1B = {0.f, 0.f, 0.f, 0.f};
    #pragma unroll
    for (int kt = 0; kt < 4; ++kt) {
      bf16x8 d0h = nd0h, d0l = nd0l, d1h = nd1h, d1l = nd1l;
      if (kt < 3) {
        nd0h = *(const bf16x8*)(D0 + (kt+1)*1024); nd0l = *(const bf16x8*)(D0 + (kt+1)*1024 + 512);
        nd1h = *(const bf16x8*)(D1 + (kt+1)*1024); nd1l = *(const bf16x8*)(D1 + (kt+1)*1024 + 512);
      }
      const unsigned short* ap = H1A + (mt*4 + kt) * 1024 + fslot(l, kt) * 8;
      bf16x8 ah = *(const bf16x8*)ap, al = *(const bf16x8*)(ap + 512);
      a0A = MFMA(ah, d0h, a0A, 0,0,0); a0B = MFMA(ah, d0l, a0B, 0,0,0); a0B = MFMA(al, d0h, a0B, 0,0,0);
      a1A = MFMA(ah, d1h, a1A, 0,0,0); a1B = MFMA(ah, d1l, a1B, 0,0,0); a1B = MFMA(al, d1h, a1B, 0,0,0);
    }
    #pragma unroll
    for (int t2 = 0; t2 < 2; ++t2) {
      int nt = m0 + t2;
      int kt2 = nt >> 1;
      int sb = 16 * ((2*nt + (c16 >> 3)) & 3);
      unsigned short* tb = H2A + (mt*8 + kt2) * 1024;
      #pragma unroll
      for (int i = 0; i < 4; ++i) {
        float v = t2 ? fmaxf(a1A[i] + a1B[i], 0.f) : fmaxf(a0A[i] + a0B[i], 0.f);
        int idx = fslot(4*g + i + sb, kt2) * 8 + (c16 & 7);
        unsigned short h = f2bf(v);
        tb[idx] = h; tb[512 + idx] = f2bf(v - bf2f(h));
      }
    }
  }
  __syncthreads();   // B3: H2A/HV2A ready

  // ---- P5: V3+L3 via MFMA (unique owners -> plain LDS stores, no atomics)
  if (w < 4) {        // L3: tile (lmt = w>>1, lnt = w&1), K=256
    const int lmt = w >> 1, lnt = w & 1;
    const unsigned short* F3 = wsU + OFF_F3*2 + (lnt*8)*1024 + l*8;
    f32x4 aA = {0.f, 0.f, 0.f, 0.f}, aB = {0.f, 0.f, 0.f, 0.f};
    bf16x8 nbh = *(const bf16x8*)F3, nbl = *(const bf16x8*)(F3 + 512);
    #pragma unroll
    for (int kt = 0; kt < 8; ++kt) {
      bf16x8 bh = nbh, bl = nbl;
      if (kt < 7) {
        nbh = *(const bf16x8*)(F3 + (kt+1)*1024); nbl = *(const bf16x8*)(F3 + (kt+1)*1024 + 512);
      }
      const unsigned short* ap = H2A + (lmt*8 + kt) * 1024 + fslot(l, kt) * 8;
      bf16x8 ah = *(const bf16x8*)ap, al = *(const bf16x8*)(ap + 512);
      aA = MFMA(ah, bh, aA, 0,0,0); aB = MFMA(ah, bl, aB, 0,0,0); aB = MFMA(al, bh, aB, 0,0,0);
    }
    #pragma unroll
    for (int i = 0; i < 4; ++i) {
      int r = lmt*16 + 4*g + i, c = lnt*16 + c16;
      if (c < 20) cpbuf[r*20 + c] = aA[i] + aB[i];
    }
  } else if (w < 6) { // V3: tile (vmt = w-4), K=128
    const int vmt = w - 4;
    const unsigned short* FV = wsU + OFF_FV3*2 + l*8;
    f32x4 aA = {0.f, 0.f, 0.f, 0.f}, aB = {0.f, 0.f, 0.f, 0.f};
    #pragma unroll
    for (int kt = 0; kt < 4; ++kt) {
      bf16x8 bh = *(const bf16x8*)(FV + kt*1024), bl = *(const bf16x8*)(FV + kt*1024 + 512);
      const unsigned short* ap = HV2A + (vmt*4 + kt) * 1024 + fslot(l, kt) * 8;
      bf16x8 ah = *(const bf16x8*)ap, al = *(const bf16x8*)(ap + 512);
      aA = MFMA(ah, bh, aA, 0,0,0); aB = MFMA(ah, bl, aB, 0,0,0); aB = MFMA(al, bh, aB, 0,0,0);
    }
    #pragma unroll
    for (int i = 0; i < 4; ++i) {
      int r = vmt*16 + 4*g + i;
      if (c16 < 10) vbuf[r*10 + c16] = aA[i] + aB[i];
    }
  }
  __syncthreads();   // B4: vbuf(logits) + cpbuf(cp sums) ready

  // ---- P6: softmax + wm (tid<32, one row each)
  if (tid < 32) {
    float lg[10]; float m = -1e30f;
    #pragma unroll
    for (int j = 0; j < 10; ++j) { lg[j] = vbuf[tid*10 + j] + wb3[j]; m = fmaxf(m, lg[j]); }
    float s = 0.f;
    #pragma unroll
    for (int j = 0; j < 10; ++j) { float e = expf(lg[j] - m); lg[j] = e; s += e; }
    float inv = __builtin_amdgcn_rcpf(s);
    #pragma unroll
    for (int j = 0; j < 10; ++j) vbuf[tid*10 + j] = lg[j] * inv;
    #pragma unroll
    for (int p = 0; p < 10; ++p) {
      float s0 = cpbuf[tid*20 + 2*p]     + cb3[2*p];
      float s1 = cpbuf[tid*20 + 2*p + 1] + cb3[2*p + 1];
      float cm = 0.5f * (tanhf(s0) + tanhf(s1));
      cpbuf[tid*20 + p] = vbuf[tid*10 + p] * cm;
    }
  }
  __syncthreads();   // B5

  // ---- P7: combine + output. thread = 2 consecutive f-cols x 32 rows.
  {
    const float* BAS = ws + OFF_BASIS;
    const int f0 = tid * 2;
    float bas[20];
    {
      const float4* bp = (const float4*)(BAS + f0 * 10);
      #pragma unroll
      for (int i = 0; i < 5; ++i) {
        float4 v = bp[i];
        bas[4*i+0] = v.x; bas[4*i+1] = v.y; bas[4*i+2] = v.z; bas[4*i+3] = v.w;
      }
    }
    for (int rr = 0; rr < 32; ++rr) {
      float wv[10], wm[10];
      #pragma unroll
      for (int p = 0; p < 10; p += 2) {
        float2 a = *(const float2*)(vbuf + rr*10 + p);
        wv[p] = a.x; wv[p+1] = a.y;
        float2 b = *(const float2*)(cpbuf + rr*20 + p);
        wm[p] = b.x; wm[p+1] = b.y;
      }
      float n0 = 0.f, d0 = EPS, n1 = 0.f, d1 = EPS;
      #pragma unroll
      for (int p = 0; p < 10; ++p) {
        n0 = fmaf(bas[p],      wm[p], n0);
        d0 = fmaf(bas[p],      wv[p], d0);
        n1 = fmaf(bas[10 + p], wm[p], n1);
        d1 = fmaf(bas[10 + p], wv[p], d1);
      }
      float2 o;
      o.x = n0 * __builtin_amdgcn_rcpf(d0);
      o.y = n1 * __builtin_amdgcn_rcpf(d1);
      *(float2*)(out + (size_t)(b0 + rr) * 1024 + f0) = o;
    }
  }
}

// ---------------------------------------------------------------------------
extern "C" void kernel_launch(void* const* d_in, const int* in_sizes, int n_in,
                              void* d_out, int out_size, void* d_ws, size_t ws_size,
                              hipStream_t stream)
{
  const float* x   = (const float*)d_in[0];
  const float* cw1 = (const float*)d_in[1];
  const float* cb1 = (const float*)d_in[2];
  const float* cw2 = (const float*)d_in[3];
  const float* cb2 = (const float*)d_in[4];
  const float* cw3 = (const float*)d_in[5];
  const float* cb3 = (const float*)d_in[6];
  const float* ww1 = (const float*)d_in[7];
  const float* wb1 = (const float*)d_in[8];
  const float* ww2 = (const float*)d_in[9];
  const float* wb2 = (const float*)d_in[10];
  const float* ww3 = (const float*)d_in[11];
  const float* wb3 = (const float*)d_in[12];
  float* ws  = (float*)d_ws;
  float* out = (float*)d_out;

  prep_kernel<<<41, 256, 0, stream>>>(cw1, cw2, cw3, ww1, ww2, ww3, ws);
  fused_kernel<<<512, 512, 0, stream>>>(x, cb1, cb2, cb3, wb1, wb2, wb3, ws, out);
}